// Round 1
// baseline (3557.685 us; speedup 1.0000x reference)
//
#include <hip/hip_runtime.h>
#include <math.h>

typedef __attribute__((ext_vector_type(8))) short short8;
typedef __attribute__((ext_vector_type(4))) float f32x4;

#define DEV static __device__ __forceinline__

DEV unsigned short f2bf(float f) {
  union { float f; unsigned u; } x; x.f = f;
  unsigned r = x.u + 0x7fffu + ((x.u >> 16) & 1u);
  return (unsigned short)(r >> 16);
}

DEV void gload_lds16(const void* gp, void* lp) {
  __builtin_amdgcn_global_load_lds(
      (const __attribute__((address_space(1))) void*)gp,
      (__attribute__((address_space(3))) void*)lp, 16, 0, 0);
}

// ---------------- weight transpose + bf16 convert: W[K][N] f32 -> Wt[N][K] bf16
__global__ __launch_bounds__(256) void wconv_t(const float* __restrict__ W,
                                               unsigned short* __restrict__ Wt,
                                               int K, int N) {
  __shared__ float tile[32][33];
  int n0 = blockIdx.x * 32, k0 = blockIdx.y * 32;
  int tx = threadIdx.x, ty = threadIdx.y;  // 32 x 8
  for (int i = ty; i < 32; i += 8)
    tile[i][tx] = W[(size_t)(k0 + i) * N + n0 + tx];
  __syncthreads();
  for (int i = ty; i < 32; i += 8)
    Wt[(size_t)(n0 + i) * K + k0 + tx] = f2bf(tile[tx][i]);
}

// ---------------- layernorm (ref semantics: var over n-1, eps added to sqrt) f32 -> bf16
__global__ __launch_bounds__(256) void ln_kernel(const float* __restrict__ hbuf,
                                                 const float* __restrict__ g,
                                                 const float* __restrict__ be,
                                                 unsigned short* __restrict__ y) {
  int row = blockIdx.x, tid = threadIdx.x;
  const float4 xv = reinterpret_cast<const float4*>(hbuf + (size_t)row * 1024)[tid];
  __shared__ float sbuf[4], sbuf2[4];
  float s = xv.x + xv.y + xv.z + xv.w;
  for (int off = 32; off; off >>= 1) s += __shfl_down(s, off);
  if ((tid & 63) == 0) sbuf[tid >> 6] = s;
  __syncthreads();
  float mean = (sbuf[0] + sbuf[1] + sbuf[2] + sbuf[3]) * (1.0f / 1024.0f);
  float d0 = xv.x - mean, d1 = xv.y - mean, d2 = xv.z - mean, d3 = xv.w - mean;
  float ss = d0 * d0 + d1 * d1 + d2 * d2 + d3 * d3;
  for (int off = 32; off; off >>= 1) ss += __shfl_down(ss, off);
  if ((tid & 63) == 0) sbuf2[tid >> 6] = ss;
  __syncthreads();
  float var = (sbuf2[0] + sbuf2[1] + sbuf2[2] + sbuf2[3]) * (1.0f / 1023.0f);
  float rs = 1.0f / (sqrtf(var) + 1e-6f);
  const float4 gv = reinterpret_cast<const float4*>(g)[tid];
  const float4 bv = reinterpret_cast<const float4*>(be)[tid];
  ushort4 o;
  o.x = f2bf(gv.x * d0 * rs + bv.x);
  o.y = f2bf(gv.y * d1 * rs + bv.y);
  o.z = f2bf(gv.z * d2 * rs + bv.z);
  o.w = f2bf(gv.w * d3 * rs + bv.w);
  reinterpret_cast<ushort4*>(y + (size_t)row * 1024)[tid] = o;
}

// ---------------- GEMM: C = A(MxK,bf16) @ Bt(NxK,bf16)^T + bias
// EPI 0: bf16 store; EPI 1: relu -> bf16; EPI 2: f32 residual +=
template <int EPI>
__global__ __launch_bounds__(256) void gemm_bt(const unsigned short* __restrict__ A,
                                               const unsigned short* __restrict__ Bt,
                                               const float* __restrict__ bias,
                                               unsigned short* __restrict__ Cb,
                                               float* __restrict__ Cf,
                                               int M, int N, int K) {
  __shared__ unsigned short As[128 * 32];
  __shared__ unsigned short Bs[128 * 32];
  const int tid = threadIdx.x, wave = tid >> 6, lane = tid & 63;
  const int fr = lane & 15, fq = lane >> 4;
  const int nbn = N >> 7;
  const int bm = blockIdx.x / nbn, bn = blockIdx.x % nbn;
  const int m0 = bm << 7, n0 = bn << 7;
  const int wm = (wave >> 1) << 6, wn = (wave & 1) << 6;
  f32x4 acc[4][4] = {};
  // staging: per lane, 2 insts each for A,B. LDS byte o = t*4096 + wave*1024 + lane*16.
  // stored chunk c2 at LDS must hold global chunk c2 ^ ((row>>1)&3)  (XOR swizzle, both sides)
  int row_a[2], col_a[2];
#pragma unroll
  for (int t = 0; t < 2; ++t) {
    int o = t * 4096 + wave * 1024 + lane * 16;
    int r = o >> 6, c2 = (o >> 4) & 3;
    row_a[t] = r;
    col_a[t] = (c2 ^ ((r >> 1) & 3)) << 3;
  }
  const unsigned short* Abase = A + (size_t)m0 * K;
  const unsigned short* Bbase = Bt + (size_t)n0 * K;
  char* AsB = (char*)As;
  char* BsB = (char*)Bs;

  for (int k0 = 0; k0 < K; k0 += 32) {
#pragma unroll
    for (int t = 0; t < 2; ++t) {
      gload_lds16(Abase + (size_t)row_a[t] * K + k0 + col_a[t], AsB + t * 4096 + wave * 1024);
      gload_lds16(Bbase + (size_t)row_a[t] * K + k0 + col_a[t], BsB + t * 4096 + wave * 1024);
    }
    __syncthreads();
    short8 af[4], bfr[4];
#pragma unroll
    for (int i = 0; i < 4; ++i) {
      int r = wm + i * 16 + fr;
      af[i] = *(const short8*)(AsB + r * 64 + ((fq ^ ((r >> 1) & 3)) << 4));
    }
#pragma unroll
    for (int j = 0; j < 4; ++j) {
      int r = wn + j * 16 + fr;
      bfr[j] = *(const short8*)(BsB + r * 64 + ((fq ^ ((r >> 1) & 3)) << 4));
    }
#pragma unroll
    for (int i = 0; i < 4; ++i)
#pragma unroll
      for (int j = 0; j < 4; ++j)
        acc[i][j] = __builtin_amdgcn_mfma_f32_16x16x32_bf16(af[i], bfr[j], acc[i][j], 0, 0, 0);
    __syncthreads();
  }
#pragma unroll
  for (int j = 0; j < 4; ++j) {
    int gcol = n0 + wn + j * 16 + fr;
    float bv = bias[gcol];
#pragma unroll
    for (int i = 0; i < 4; ++i) {
      int grow = m0 + wm + i * 16 + fq * 4;
#pragma unroll
      for (int r = 0; r < 4; ++r) {
        float val = acc[i][j][r] + bv;
        if (EPI == 1) val = fmaxf(val, 0.0f);
        if (EPI == 2) {
          size_t idx = (size_t)(grow + r) * N + gcol;
          Cf[idx] += val;
        } else {
          Cb[(size_t)(grow + r) * N + gcol] = f2bf(val);
        }
      }
    }
  }
}

// ---------------- flash attention: q,k,v,out all [B][S][H*64] bf16, non-causal, scale=0.125
__global__ __launch_bounds__(256) void attn_kernel(const unsigned short* __restrict__ Q,
                                                   const unsigned short* __restrict__ Kg,
                                                   const unsigned short* __restrict__ V,
                                                   unsigned short* __restrict__ Aout) {
  const int S = 1024, HD = 1024;
  const int bh = blockIdx.x;  // b*16+h
  const int b = bh >> 4, hh = bh & 15;
  const int q0 = blockIdx.y << 6;
  const int tid = threadIdx.x, wave = tid >> 6, lane = tid & 63;
  const int fr = lane & 15, fq = lane >> 4;

  __shared__ unsigned short Ks[64][72];
  __shared__ unsigned short Vt[64][72];
  __shared__ unsigned short Pl[4][16][72];

  const size_t base = ((size_t)b * S) * HD + hh * 64;
  short8 qf[2];
  {
    int qrow = q0 + wave * 16 + fr;
    const unsigned short* qp = Q + base + (size_t)qrow * HD + fq * 8;
    qf[0] = *(const short8*)(qp);
    qf[1] = *(const short8*)(qp + 32);
  }
  float m_r[4] = {-INFINITY, -INFINITY, -INFINITY, -INFINITY};
  float l_r[4] = {0.f, 0.f, 0.f, 0.f};
  f32x4 oa[4] = {};

  for (int kv0 = 0; kv0 < S; kv0 += 64) {
    {  // stage K rows + V transposed
      int rr = tid >> 3, seg = tid & 7;
      const unsigned short* kp = Kg + base + (size_t)(kv0 + rr) * HD + seg * 8;
      *(short8*)&Ks[rr][seg * 8] = *(const short8*)kp;
      *(short8*)&Ks[rr + 32][seg * 8] = *(const short8*)(kp + 32 * HD);
      const unsigned short* vp = V + base + (size_t)(kv0 + rr) * HD + seg * 8;
      short8 v0 = *(const short8*)vp;
      short8 v1 = *(const short8*)(vp + 32 * HD);
#pragma unroll
      for (int j = 0; j < 8; ++j) {
        Vt[seg * 8 + j][rr] = (unsigned short)v0[j];
        Vt[seg * 8 + j][rr + 32] = (unsigned short)v1[j];
      }
    }
    __syncthreads();
    f32x4 sf[4];
#pragma unroll
    for (int fn = 0; fn < 4; ++fn) {
      f32x4 z = {};
      short8 kf0 = *(const short8*)&Ks[fn * 16 + fr][fq * 8];
      short8 kf1 = *(const short8*)&Ks[fn * 16 + fr][32 + fq * 8];
      z = __builtin_amdgcn_mfma_f32_16x16x32_bf16(qf[0], kf0, z, 0, 0, 0);
      z = __builtin_amdgcn_mfma_f32_16x16x32_bf16(qf[1], kf1, z, 0, 0, 0);
      sf[fn] = z * 0.125f;
    }
    float pr[4][4];
#pragma unroll
    for (int r = 0; r < 4; ++r) {
      float mx = fmaxf(fmaxf(sf[0][r], sf[1][r]), fmaxf(sf[2][r], sf[3][r]));
#pragma unroll
      for (int off = 1; off < 16; off <<= 1) mx = fmaxf(mx, __shfl_xor(mx, off));
      float mn = fmaxf(m_r[r], mx);
      float al = __expf(m_r[r] - mn);
      float rsum = 0.f;
#pragma unroll
      for (int fn = 0; fn < 4; ++fn) {
        float p = __expf(sf[fn][r] - mn);
        pr[fn][r] = p;
        rsum += p;
      }
#pragma unroll
      for (int off = 1; off < 16; off <<= 1) rsum += __shfl_xor(rsum, off);
      l_r[r] = l_r[r] * al + rsum;
      m_r[r] = mn;
#pragma unroll
      for (int fn = 0; fn < 4; ++fn) oa[fn][r] *= al;
    }
#pragma unroll
    for (int fn = 0; fn < 4; ++fn)
#pragma unroll
      for (int r = 0; r < 4; ++r)
        Pl[wave][fq * 4 + r][fn * 16 + fr] = f2bf(pr[fn][r]);
#pragma unroll
    for (int ks = 0; ks < 2; ++ks) {
      short8 pa = *(const short8*)&Pl[wave][fr][ks * 32 + fq * 8];
#pragma unroll
      for (int fn = 0; fn < 4; ++fn) {
        short8 vf = *(const short8*)&Vt[fn * 16 + fr][ks * 32 + fq * 8];
        oa[fn] = __builtin_amdgcn_mfma_f32_16x16x32_bf16(pa, vf, oa[fn], 0, 0, 0);
      }
    }
    __syncthreads();
  }
#pragma unroll
  for (int r = 0; r < 4; ++r) {
    float inv = 1.0f / l_r[r];
    int grow = q0 + wave * 16 + fq * 4 + r;
#pragma unroll
    for (int fn = 0; fn < 4; ++fn)
      Aout[base + (size_t)grow * HD + fn * 16 + fr] = f2bf(oa[fn][r] * inv);
  }
}

// ---------------- final LN (last token) + FC + softmax
__global__ __launch_bounds__(256) void head_kernel(const float* __restrict__ hbuf,
                                                   const float* __restrict__ g,
                                                   const float* __restrict__ be,
                                                   const float* __restrict__ Wfc,
                                                   const float* __restrict__ bfc,
                                                   float* __restrict__ out) {
  int b = blockIdx.x, tid = threadIdx.x;
  const float* x = hbuf + ((size_t)b * 1024 + 1023) * 1024;
  __shared__ float sbuf[4], sbuf2[4];
  __shared__ float ybuf[1024];
  __shared__ float part[16][17];
  float4 xv = reinterpret_cast<const float4*>(x)[tid];
  float s = xv.x + xv.y + xv.z + xv.w;
  for (int off = 32; off; off >>= 1) s += __shfl_down(s, off);
  if ((tid & 63) == 0) sbuf[tid >> 6] = s;
  __syncthreads();
  float mean = (sbuf[0] + sbuf[1] + sbuf[2] + sbuf[3]) * (1.0f / 1024.0f);
  float d0 = xv.x - mean, d1 = xv.y - mean, d2 = xv.z - mean, d3 = xv.w - mean;
  float ss = d0 * d0 + d1 * d1 + d2 * d2 + d3 * d3;
  for (int off = 32; off; off >>= 1) ss += __shfl_down(ss, off);
  if ((tid & 63) == 0) sbuf2[tid >> 6] = ss;
  __syncthreads();
  float var = (sbuf2[0] + sbuf2[1] + sbuf2[2] + sbuf2[3]) * (1.0f / 1023.0f);
  float rs = 1.0f / (sqrtf(var) + 1e-6f);
  const float4 gv = reinterpret_cast<const float4*>(g)[tid];
  const float4 bv = reinterpret_cast<const float4*>(be)[tid];
  float4 yv;
  yv.x = gv.x * d0 * rs + bv.x;
  yv.y = gv.y * d1 * rs + bv.y;
  yv.z = gv.z * d2 * rs + bv.z;
  yv.w = gv.w * d3 * rs + bv.w;
  reinterpret_cast<float4*>(ybuf)[tid] = yv;
  __syncthreads();
  int n = tid & 15, pg = tid >> 4;
  float acc = 0.f;
  for (int kk = 0; kk < 64; ++kk) acc += ybuf[pg * 64 + kk] * Wfc[(size_t)(pg * 64 + kk) * 16 + n];
  part[pg][n] = acc;
  __syncthreads();
  if (tid < 16) {
    float lg = bfc[tid];
    for (int p = 0; p < 16; ++p) lg += part[p][tid];
    ybuf[tid] = lg;
  }
  __syncthreads();
  if (tid == 0) {
    float mx = ybuf[0];
    for (int i = 1; i < 16; ++i) mx = fmaxf(mx, ybuf[i]);
    float se = 0.f;
    float e[16];
    for (int i = 0; i < 16; ++i) { e[i] = __expf(ybuf[i] - mx); se += e[i]; }
    float is = 1.0f / se;
    for (int i = 0; i < 16; ++i) out[b * 16 + i] = e[i] * is;
  }
}

extern "C" void kernel_launch(void* const* d_in, const int* in_sizes, int n_in,
                              void* d_out, int out_size, void* d_ws, size_t ws_size,
                              hipStream_t stream) {
  const int B = 8, S = 1024, D = 1024, F = 4096, NL = 6;
  const int M = B * S;
  const float* x1 = (const float*)d_in[0];
  const float* Wq = (const float*)d_in[1];
  const float* bq = (const float*)d_in[2];
  const float* Wk = (const float*)d_in[3];
  const float* bk = (const float*)d_in[4];
  const float* Wv = (const float*)d_in[5];
  const float* bv = (const float*)d_in[6];
  const float* Wo = (const float*)d_in[7];
  const float* bo = (const float*)d_in[8];
  const float* ln0g = (const float*)d_in[9];
  const float* ln0b = (const float*)d_in[10];
  const float* W1 = (const float*)d_in[11];
  const float* b1 = (const float*)d_in[12];
  const float* W2 = (const float*)d_in[13];
  const float* b2 = (const float*)d_in[14];
  const float* ln1g = (const float*)d_in[15];
  const float* ln1b = (const float*)d_in[16];
  const float* lnFg = (const float*)d_in[17];
  const float* lnFb = (const float*)d_in[18];
  const float* Wfc = (const float*)d_in[19];
  const float* bfc = (const float*)d_in[20];

  char* ws = (char*)d_ws;
  size_t off = 0;
  auto carve = [&](size_t bytes) {
    char* p = ws + off;
    off += (bytes + 255) & ~(size_t)255;
    return p;
  };
  float* h = (float*)carve((size_t)M * D * 4);
  unsigned short* y = (unsigned short*)carve((size_t)M * D * 2);
  unsigned short* qb = (unsigned short*)carve((size_t)M * D * 2);
  unsigned short* kb = (unsigned short*)carve((size_t)M * D * 2);
  unsigned short* vb = (unsigned short*)carve((size_t)M * D * 2);
  unsigned short* ab = (unsigned short*)carve((size_t)M * D * 2);
  unsigned short* tb = (unsigned short*)carve((size_t)M * F * 2);
  unsigned short* wtq = (unsigned short*)carve((size_t)D * D * 2);
  unsigned short* wtk = (unsigned short*)carve((size_t)D * D * 2);
  unsigned short* wtv = (unsigned short*)carve((size_t)D * D * 2);
  unsigned short* wto = (unsigned short*)carve((size_t)D * D * 2);
  unsigned short* wt1 = (unsigned short*)carve((size_t)D * F * 2);
  unsigned short* wt2 = (unsigned short*)carve((size_t)F * D * 2);

  hipMemcpyAsync(h, x1, (size_t)M * D * 4, hipMemcpyDeviceToDevice, stream);

  dim3 tblk(32, 8);
  const int gDD = (M / 128) * (D / 128);
  const int gDF = (M / 128) * (F / 128);
  for (int l = 0; l < NL; ++l) {
    wconv_t<<<dim3(D / 32, D / 32), tblk, 0, stream>>>(Wq + (size_t)l * D * D, wtq, D, D);
    wconv_t<<<dim3(D / 32, D / 32), tblk, 0, stream>>>(Wk + (size_t)l * D * D, wtk, D, D);
    wconv_t<<<dim3(D / 32, D / 32), tblk, 0, stream>>>(Wv + (size_t)l * D * D, wtv, D, D);
    wconv_t<<<dim3(D / 32, D / 32), tblk, 0, stream>>>(Wo + (size_t)l * D * D, wto, D, D);
    wconv_t<<<dim3(F / 32, D / 32), tblk, 0, stream>>>(W1 + (size_t)l * D * F, wt1, D, F);
    wconv_t<<<dim3(D / 32, F / 32), tblk, 0, stream>>>(W2 + (size_t)l * F * D, wt2, F, D);

    ln_kernel<<<M, 256, 0, stream>>>(h, ln0g + (size_t)l * D, ln0b + (size_t)l * D, y);
    gemm_bt<0><<<gDD, 256, 0, stream>>>(y, wtq, bq + (size_t)l * D, qb, nullptr, M, D, D);
    gemm_bt<0><<<gDD, 256, 0, stream>>>(y, wtk, bk + (size_t)l * D, kb, nullptr, M, D, D);
    gemm_bt<0><<<gDD, 256, 0, stream>>>(y, wtv, bv + (size_t)l * D, vb, nullptr, M, D, D);
    attn_kernel<<<dim3(B * 16, S / 64), 256, 0, stream>>>(qb, kb, vb, ab);
    gemm_bt<2><<<gDD, 256, 0, stream>>>(ab, wto, bo + (size_t)l * D, nullptr, h, M, D, D);
    ln_kernel<<<M, 256, 0, stream>>>(h, ln1g + (size_t)l * D, ln1b + (size_t)l * D, y);
    gemm_bt<1><<<gDF, 256, 0, stream>>>(y, wt1, b1 + (size_t)l * F, tb, nullptr, M, F, D);
    gemm_bt<2><<<gDD, 256, 0, stream>>>(tb, wt2, b2 + (size_t)l * D, nullptr, h, M, D, F);
  }
  head_kernel<<<B, 256, 0, stream>>>(h, lnFg, lnFb, Wfc, bfc, (float*)d_out);
}

// Round 3
// 2919.290 us; speedup vs baseline: 1.2187x; 1.2187x over previous
//
#include <hip/hip_runtime.h>
#include <math.h>

typedef unsigned short ushort;
typedef __attribute__((ext_vector_type(8))) short short8;
typedef __attribute__((ext_vector_type(4))) float f32x4;

#define DEV static __device__ __forceinline__

DEV ushort f2bf(float f) {
  union { float f; unsigned u; } x; x.f = f;
  unsigned r = x.u + 0x7fffu + ((x.u >> 16) & 1u);
  return (ushort)(r >> 16);
}

DEV void gload_lds16(const void* gp, void* lp) {
  __builtin_amdgcn_global_load_lds(
      (const __attribute__((address_space(1))) void*)gp,
      (__attribute__((address_space(3))) void*)lp, 16, 0, 0);
}

// ---------------- weight transpose + bf16 convert: W[K][N] f32 -> Wt[N][K] bf16
__global__ __launch_bounds__(256) void wconv_t(const float* __restrict__ W,
                                               ushort* __restrict__ Wt,
                                               int K, int N) {
  __shared__ float tile[32][33];
  int n0 = blockIdx.x * 32, k0 = blockIdx.y * 32;
  int tx = threadIdx.x, ty = threadIdx.y;  // 32 x 8
  for (int i = ty; i < 32; i += 8)
    tile[i][tx] = W[(size_t)(k0 + i) * N + n0 + tx];
  __syncthreads();
  for (int i = ty; i < 32; i += 8)
    Wt[(size_t)(n0 + i) * K + k0 + tx] = f2bf(tile[tx][i]);
}

// qkv fused: three D x D weights -> Wt[3072][1024]
__global__ __launch_bounds__(256) void wconv_qkv(const float* __restrict__ Wq,
                                                 const float* __restrict__ Wk,
                                                 const float* __restrict__ Wv,
                                                 ushort* __restrict__ Wt) {
  __shared__ float tile[32][33];
  const float* W = blockIdx.z == 0 ? Wq : (blockIdx.z == 1 ? Wk : Wv);
  ushort* dst = Wt + (size_t)blockIdx.z * 1024 * 1024;
  int n0 = blockIdx.x * 32, k0 = blockIdx.y * 32;
  int tx = threadIdx.x, ty = threadIdx.y;
  for (int i = ty; i < 32; i += 8)
    tile[i][tx] = W[(size_t)(k0 + i) * 1024 + n0 + tx];
  __syncthreads();
  for (int i = ty; i < 32; i += 8)
    dst[(size_t)(n0 + i) * 1024 + k0 + tx] = f2bf(tile[tx][i]);
}

__global__ __launch_bounds__(256) void bias_cat(const float* __restrict__ bq,
                                                const float* __restrict__ bk,
                                                const float* __restrict__ bv,
                                                float* __restrict__ bcat) {
  int i = blockIdx.x * 256 + threadIdx.x;  // 6*3072 total
  int l = i / 3072, j = i - l * 3072;
  float v = j < 1024 ? bq[l * 1024 + j]
                     : (j < 2048 ? bk[l * 1024 + j - 1024] : bv[l * 1024 + j - 2048]);
  bcat[i] = v;
}

// ---------------- layernorm (ref: var over n-1, eps added to sqrt) f32 -> bf16
__global__ __launch_bounds__(256) void ln_kernel(const float* __restrict__ hbuf,
                                                 const float* __restrict__ g,
                                                 const float* __restrict__ be,
                                                 ushort* __restrict__ y) {
  int row = blockIdx.x, tid = threadIdx.x;
  const float4 xv = reinterpret_cast<const float4*>(hbuf + (size_t)row * 1024)[tid];
  __shared__ float sbuf[4], sbuf2[4];
  float s = xv.x + xv.y + xv.z + xv.w;
  for (int off = 32; off; off >>= 1) s += __shfl_down(s, off);
  if ((tid & 63) == 0) sbuf[tid >> 6] = s;
  __syncthreads();
  float mean = (sbuf[0] + sbuf[1] + sbuf[2] + sbuf[3]) * (1.0f / 1024.0f);
  float d0 = xv.x - mean, d1 = xv.y - mean, d2 = xv.z - mean, d3 = xv.w - mean;
  float ss = d0 * d0 + d1 * d1 + d2 * d2 + d3 * d3;
  for (int off = 32; off; off >>= 1) ss += __shfl_down(ss, off);
  if ((tid & 63) == 0) sbuf2[tid >> 6] = ss;
  __syncthreads();
  float var = (sbuf2[0] + sbuf2[1] + sbuf2[2] + sbuf2[3]) * (1.0f / 1023.0f);
  float rs = 1.0f / (sqrtf(var) + 1e-6f);
  const float4 gv = reinterpret_cast<const float4*>(g)[tid];
  const float4 bv = reinterpret_cast<const float4*>(be)[tid];
  ushort4 o;
  o.x = f2bf(gv.x * d0 * rs + bv.x);
  o.y = f2bf(gv.y * d1 * rs + bv.y);
  o.z = f2bf(gv.z * d2 * rs + bv.z);
  o.w = f2bf(gv.w * d3 * rs + bv.w);
  reinterpret_cast<ushort4*>(y + (size_t)row * 1024)[tid] = o;
}

// ---------------- GEMM: C = A(MxK,bf16) @ Bt(NxK,bf16)^T + bias
// EPI 0: bf16 store; EPI 1: relu -> bf16; EPI 2: f32 residual +=
template <int EPI>
__global__ __launch_bounds__(256) void gemm_bt(const ushort* __restrict__ A,
                                               const ushort* __restrict__ Bt,
                                               const float* __restrict__ bias,
                                               ushort* __restrict__ Cb,
                                               float* __restrict__ Cf,
                                               int M, int N, int K) {
  __shared__ ushort As[128 * 32];
  __shared__ ushort Bs[128 * 32];
  const int tid = threadIdx.x, wave = tid >> 6, lane = tid & 63;
  const int fr = lane & 15, fq = lane >> 4;
  const int nbn = N >> 7;
  // T1: XCD-aware swizzle (gridDim.x always % 8 == 0 here -> bijective)
  const int cpx = gridDim.x >> 3;
  const int sb = (blockIdx.x & 7) * cpx + (blockIdx.x >> 3);
  const int bm = sb / nbn, bn = sb % nbn;
  const int m0 = bm << 7, n0 = bn << 7;
  const int wm = (wave >> 1) << 6, wn = (wave & 1) << 6;
  f32x4 acc[4][4] = {};
  int row_a[2], col_a[2];
#pragma unroll
  for (int t = 0; t < 2; ++t) {
    int o = t * 4096 + wave * 1024 + lane * 16;
    int r = o >> 6, c2 = (o >> 4) & 3;
    row_a[t] = r;
    col_a[t] = (c2 ^ ((r >> 1) & 3)) << 3;
  }
  const ushort* Abase = A + (size_t)m0 * K;
  const ushort* Bbase = Bt + (size_t)n0 * K;
  char* AsB = (char*)As;
  char* BsB = (char*)Bs;

  for (int k0 = 0; k0 < K; k0 += 32) {
#pragma unroll
    for (int t = 0; t < 2; ++t) {
      gload_lds16(Abase + (size_t)row_a[t] * K + k0 + col_a[t], AsB + t * 4096 + wave * 1024);
      gload_lds16(Bbase + (size_t)row_a[t] * K + k0 + col_a[t], BsB + t * 4096 + wave * 1024);
    }
    __syncthreads();
    short8 af[4], bfr[4];
#pragma unroll
    for (int i = 0; i < 4; ++i) {
      int r = wm + i * 16 + fr;
      af[i] = *(const short8*)(AsB + r * 64 + ((fq ^ ((r >> 1) & 3)) << 4));
    }
#pragma unroll
    for (int j = 0; j < 4; ++j) {
      int r = wn + j * 16 + fr;
      bfr[j] = *(const short8*)(BsB + r * 64 + ((fq ^ ((r >> 1) & 3)) << 4));
    }
    __builtin_amdgcn_s_setprio(1);
#pragma unroll
    for (int i = 0; i < 4; ++i)
#pragma unroll
      for (int j = 0; j < 4; ++j)
        acc[i][j] = __builtin_amdgcn_mfma_f32_16x16x32_bf16(af[i], bfr[j], acc[i][j], 0, 0, 0);
    __builtin_amdgcn_s_setprio(0);
    __syncthreads();
  }
#pragma unroll
  for (int j = 0; j < 4; ++j) {
    int gcol = n0 + wn + j * 16 + fr;
    float bv = bias[gcol];
#pragma unroll
    for (int i = 0; i < 4; ++i) {
      int grow = m0 + wm + i * 16 + fq * 4;
#pragma unroll
      for (int r = 0; r < 4; ++r) {
        float val = acc[i][j][r] + bv;
        if (EPI == 1) val = fmaxf(val, 0.0f);
        if (EPI == 2) {
          size_t idx = (size_t)(grow + r) * N + gcol;
          Cf[idx] += val;
        } else {
          Cb[(size_t)(grow + r) * N + gcol] = f2bf(val);
        }
      }
    }
  }
}

// ---------------- flash attention v3: fused qkv input [8192][3072] bf16
// Round-1-verified staging (padded Ks/Vt, scalar transpose for V) +
// swapped QK^T (mfma(K,Q) -> S^T), fully per-lane online softmax,
// P kept in registers via kv-permutation (no P LDS round-trip).
__global__ __launch_bounds__(256) void attn3(const ushort* __restrict__ qkv,
                                             ushort* __restrict__ Aout) {
  const int LDQ = 3072;
  const int bh = blockIdx.x;  // b*16+h
  const int b = bh >> 4, hh = bh & 15;
  const int q0 = blockIdx.y << 6;
  const int tid = threadIdx.x, wave = tid >> 6, lane = tid & 63;
  const int fr = lane & 15, fq = lane >> 4;

  __shared__ ushort Ks[64][72];  // K[kv][d], padded
  __shared__ ushort Vt[64][72];  // V^T: Vt[d][kv], padded

  const ushort* Qb = qkv + (size_t)b * 1024 * LDQ + hh * 64;
  const ushort* Kb = Qb + 1024;
  const ushort* Vb = Qb + 2048;

  // Q fragments (B-operand): lane supplies Q[q = q0+wave*16+fr][d = fq*8..]
  short8 qf[2];
  {
    const ushort* qp = Qb + (size_t)(q0 + wave * 16 + fr) * LDQ + fq * 8;
    qf[0] = *(const short8*)(qp);
    qf[1] = *(const short8*)(qp + 32);
  }

  float m_run = -INFINITY, l_run = 0.0f;
  f32x4 oa[4] = {};

  const int rr = tid >> 3, seg = tid & 7;
  for (int kv0 = 0; kv0 < 1024; kv0 += 64) {
    {  // stage K rows + V transposed (round-1-verified pattern)
      const ushort* kp = Kb + (size_t)(kv0 + rr) * LDQ + seg * 8;
      *(short8*)&Ks[rr][seg * 8] = *(const short8*)kp;
      *(short8*)&Ks[rr + 32][seg * 8] = *(const short8*)(kp + 32 * LDQ);
      const ushort* vp = Vb + (size_t)(kv0 + rr) * LDQ + seg * 8;
      short8 v0 = *(const short8*)vp;
      short8 v1 = *(const short8*)(vp + 32 * LDQ);
#pragma unroll
      for (int j = 0; j < 8; ++j) {
        Vt[seg * 8 + j][rr] = (ushort)v0[j];
        Vt[seg * 8 + j][rr + 32] = (ushort)v1[j];
      }
    }
    __syncthreads();

    // ---- QK^T (swapped): sf[fn][r] = score(q=fr, kv=(fn&1)*32+fq*8+(fn>>1)*4+r)
    f32x4 sf[4];
    __builtin_amdgcn_s_setprio(1);
#pragma unroll
    for (int fn = 0; fn < 4; ++fn) {
      int kvr = ((fn & 1) << 5) | ((fr >> 2) << 3) | ((fn >> 1) << 2) | (fr & 3);
      short8 kf0 = *(const short8*)&Ks[kvr][fq * 8];
      short8 kf1 = *(const short8*)&Ks[kvr][32 + fq * 8];
      f32x4 z = {};
      z = __builtin_amdgcn_mfma_f32_16x16x32_bf16(kf0, qf[0], z, 0, 0, 0);
      z = __builtin_amdgcn_mfma_f32_16x16x32_bf16(kf1, qf[1], z, 0, 0, 0);
      sf[fn] = z * 0.125f;
    }
    __builtin_amdgcn_s_setprio(0);

    // ---- online softmax, fully per-lane (row q = fr)
    float mx = sf[0][0];
#pragma unroll
    for (int fn = 0; fn < 4; ++fn)
#pragma unroll
      for (int r = 0; r < 4; ++r)
        if (fn || r) mx = fmaxf(mx, sf[fn][r]);
    mx = fmaxf(mx, __shfl_xor(mx, 16));
    mx = fmaxf(mx, __shfl_xor(mx, 32));
    float mn = fmaxf(m_run, mx);
    float al = __expf(m_run - mn);
    m_run = mn;
    float p[4][4];
    float rs = 0.0f;
#pragma unroll
    for (int fn = 0; fn < 4; ++fn)
#pragma unroll
      for (int r = 0; r < 4; ++r) {
        float e = __expf(sf[fn][r] - mn);
        p[fn][r] = e;
        rs += e;
      }
    rs += __shfl_xor(rs, 16);
    rs += __shfl_xor(rs, 32);
    l_run = l_run * al + rs;
    float alo[4];
#pragma unroll
    for (int r = 0; r < 4; ++r) alo[r] = __shfl(al, (fq << 2) + r);
#pragma unroll
    for (int fn = 0; fn < 4; ++fn)
#pragma unroll
      for (int r = 0; r < 4; ++r) oa[fn][r] *= alo[r];

    // ---- P -> bf16 in-register (lane already owns its PV A-fragment)
    unsigned pw[4][2];
#pragma unroll
    for (int fn = 0; fn < 4; ++fn)
#pragma unroll
      for (int h2 = 0; h2 < 2; ++h2)
        asm("v_cvt_pk_bf16_f32 %0, %1, %2"
            : "=v"(pw[fn][h2])
            : "v"(p[fn][2 * h2]), "v"(p[fn][2 * h2 + 1]));

    // ---- PV: A = P (registers), B = V^T fragments from Vt
    __builtin_amdgcn_s_setprio(1);
#pragma unroll
    for (int ks = 0; ks < 2; ++ks) {
      union { unsigned w[4]; short8 s; } pu;
      pu.w[0] = pw[ks][0]; pu.w[1] = pw[ks][1];
      pu.w[2] = pw[ks + 2][0]; pu.w[3] = pw[ks + 2][1];
#pragma unroll
      for (int fn = 0; fn < 4; ++fn) {
        short8 vf = *(const short8*)&Vt[fn * 16 + fr][ks * 32 + fq * 8];
        oa[fn] = __builtin_amdgcn_mfma_f32_16x16x32_bf16(pu.s, vf, oa[fn], 0, 0, 0);
      }
    }
    __builtin_amdgcn_s_setprio(0);
    __syncthreads();
  }

  // ---- epilogue: O row q = fq*4+r, col d = fn*16+fr
  float linv = 1.0f / l_run;
  float li[4];
#pragma unroll
  for (int r = 0; r < 4; ++r) li[r] = __shfl(linv, (fq << 2) + r);
#pragma unroll
  for (int r = 0; r < 4; ++r) {
    size_t orow = (size_t)(b * 1024 + q0 + wave * 16 + fq * 4 + r);
#pragma unroll
    for (int fn = 0; fn < 4; ++fn)
      Aout[orow * 1024 + hh * 64 + fn * 16 + fr] = f2bf(oa[fn][r] * li[r]);
  }
}

// ---------------- final LN (last token) + FC + softmax
__global__ __launch_bounds__(256) void head_kernel(const float* __restrict__ hbuf,
                                                   const float* __restrict__ g,
                                                   const float* __restrict__ be,
                                                   const float* __restrict__ Wfc,
                                                   const float* __restrict__ bfc,
                                                   float* __restrict__ out) {
  int b = blockIdx.x, tid = threadIdx.x;
  const float* x = hbuf + ((size_t)b * 1024 + 1023) * 1024;
  __shared__ float sbuf[4], sbuf2[4];
  __shared__ float ybuf[1024];
  __shared__ float part[16][17];
  float4 xv = reinterpret_cast<const float4*>(x)[tid];
  float s = xv.x + xv.y + xv.z + xv.w;
  for (int off = 32; off; off >>= 1) s += __shfl_down(s, off);
  if ((tid & 63) == 0) sbuf[tid >> 6] = s;
  __syncthreads();
  float mean = (sbuf[0] + sbuf[1] + sbuf[2] + sbuf[3]) * (1.0f / 1024.0f);
  float d0 = xv.x - mean, d1 = xv.y - mean, d2 = xv.z - mean, d3 = xv.w - mean;
  float ss = d0 * d0 + d1 * d1 + d2 * d2 + d3 * d3;
  for (int off = 32; off; off >>= 1) ss += __shfl_down(ss, off);
  if ((tid & 63) == 0) sbuf2[tid >> 6] = ss;
  __syncthreads();
  float var = (sbuf2[0] + sbuf2[1] + sbuf2[2] + sbuf2[3]) * (1.0f / 1023.0f);
  float rs = 1.0f / (sqrtf(var) + 1e-6f);
  const float4 gv = reinterpret_cast<const float4*>(g)[tid];
  const float4 bv = reinterpret_cast<const float4*>(be)[tid];
  float4 yv;
  yv.x = gv.x * d0 * rs + bv.x;
  yv.y = gv.y * d1 * rs + bv.y;
  yv.z = gv.z * d2 * rs + bv.z;
  yv.w = gv.w * d3 * rs + bv.w;
  reinterpret_cast<float4*>(ybuf)[tid] = yv;
  __syncthreads();
  int n = tid & 15, pg = tid >> 4;
  float acc = 0.f;
  for (int kk = 0; kk < 64; ++kk) acc += ybuf[pg * 64 + kk] * Wfc[(size_t)(pg * 64 + kk) * 16 + n];
  part[pg][n] = acc;
  __syncthreads();
  if (tid < 16) {
    float lg = bfc[tid];
    for (int p = 0; p < 16; ++p) lg += part[p][tid];
    ybuf[tid] = lg;
  }
  __syncthreads();
  if (tid == 0) {
    float mx = ybuf[0];
    for (int i = 1; i < 16; ++i) mx = fmaxf(mx, ybuf[i]);
    float se = 0.f;
    float e[16];
    for (int i = 0; i < 16; ++i) { e[i] = __expf(ybuf[i] - mx); se += e[i]; }
    float is = 1.0f / se;
    for (int i = 0; i < 16; ++i) out[b * 16 + i] = e[i] * is;
  }
}

extern "C" void kernel_launch(void* const* d_in, const int* in_sizes, int n_in,
                              void* d_out, int out_size, void* d_ws, size_t ws_size,
                              hipStream_t stream) {
  const int B = 8, S = 1024, D = 1024, F = 4096, NL = 6;
  const int M = B * S;
  const float* x1 = (const float*)d_in[0];
  const float* Wq = (const float*)d_in[1];
  const float* bq = (const float*)d_in[2];
  const float* Wk = (const float*)d_in[3];
  const float* bk = (const float*)d_in[4];
  const float* Wv = (const float*)d_in[5];
  const float* bv = (const float*)d_in[6];
  const float* Wo = (const float*)d_in[7];
  const float* bo = (const float*)d_in[8];
  const float* ln0g = (const float*)d_in[9];
  const float* ln0b = (const float*)d_in[10];
  const float* W1 = (const float*)d_in[11];
  const float* b1 = (const float*)d_in[12];
  const float* W2 = (const float*)d_in[13];
  const float* b2 = (const float*)d_in[14];
  const float* ln1g = (const float*)d_in[15];
  const float* ln1b = (const float*)d_in[16];
  const float* lnFg = (const float*)d_in[17];
  const float* lnFb = (const float*)d_in[18];
  const float* Wfc = (const float*)d_in[19];
  const float* bfc = (const float*)d_in[20];

  char* ws = (char*)d_ws;
  size_t off = 0;
  auto carve = [&](size_t bytes) {
    char* p = ws + off;
    off += (bytes + 255) & ~(size_t)255;
    return p;
  };
  float* h = (float*)carve((size_t)M * D * 4);
  ushort* y = (ushort*)carve((size_t)M * D * 2);
  ushort* qkvb = (ushort*)carve((size_t)M * 3 * D * 2);
  ushort* ab = (ushort*)carve((size_t)M * D * 2);
  ushort* tb = (ushort*)carve((size_t)M * F * 2);
  ushort* wtqkv = (ushort*)carve((size_t)3 * D * D * 2);
  ushort* wto = (ushort*)carve((size_t)D * D * 2);
  ushort* wt1 = (ushort*)carve((size_t)D * F * 2);
  ushort* wt2 = (ushort*)carve((size_t)F * D * 2);
  float* bcat = (float*)carve((size_t)NL * 3 * D * 4);

  hipMemcpyAsync(h, x1, (size_t)M * D * 4, hipMemcpyDeviceToDevice, stream);
  bias_cat<<<(NL * 3 * D) / 256, 256, 0, stream>>>(bq, bk, bv, bcat);

  dim3 tblk(32, 8);
  const int gQKV = (M / 128) * ((3 * D) / 128);
  const int gDD = (M / 128) * (D / 128);
  const int gDF = (M / 128) * (F / 128);
  for (int l = 0; l < NL; ++l) {
    wconv_qkv<<<dim3(D / 32, D / 32, 3), tblk, 0, stream>>>(
        Wq + (size_t)l * D * D, Wk + (size_t)l * D * D, Wv + (size_t)l * D * D, wtqkv);
    wconv_t<<<dim3(D / 32, D / 32), tblk, 0, stream>>>(Wo + (size_t)l * D * D, wto, D, D);
    wconv_t<<<dim3(F / 32, D / 32), tblk, 0, stream>>>(W1 + (size_t)l * D * F, wt1, D, F);
    wconv_t<<<dim3(D / 32, F / 32), tblk, 0, stream>>>(W2 + (size_t)l * F * D, wt2, F, D);

    ln_kernel<<<M, 256, 0, stream>>>(h, ln0g + (size_t)l * D, ln0b + (size_t)l * D, y);
    gemm_bt<0><<<gQKV, 256, 0, stream>>>(y, wtqkv, bcat + (size_t)l * 3 * D, qkvb, nullptr,
                                         M, 3 * D, D);
    attn3<<<dim3(B * 16, S / 64), 256, 0, stream>>>(qkvb, ab);
    gemm_bt<2><<<gDD, 256, 0, stream>>>(ab, wto, bo + (size_t)l * D, nullptr, h, M, D, D);
    ln_kernel<<<M, 256, 0, stream>>>(h, ln1g + (size_t)l * D, ln1b + (size_t)l * D, y);
    gemm_bt<1><<<gDF, 256, 0, stream>>>(y, wt1, b1 + (size_t)l * F, tb, nullptr, M, F, D);
    gemm_bt<2><<<gDD, 256, 0, stream>>>(tb, wt2, b2 + (size_t)l * D, nullptr, h, M, D, F);
  }
  head_kernel<<<B, 256, 0, stream>>>(h, lnFg, lnFb, Wfc, bfc, (float*)d_out);
}